// Round 1
// baseline (519.883 us; speedup 1.0000x reference)
//
#include <hip/hip_runtime.h>

// LightGCN: deg -> norm -> 3x (gather-scale-scatter via CSR) -> mean of 4 layers.
// N=100000 nodes, E=1250000 edges, D=64 (one wave = one node's row).

#define SCAN_CHUNK 1024

__device__ __forceinline__ int wave_scan_incl(int v, int lane) {
#pragma unroll
  for (int off = 1; off < 64; off <<= 1) {
    int t = __shfl_up(v, off, 64);
    if (lane >= off) v += t;
  }
  return v;
}

// inclusive scan across the block (blockDim.x multiple of 64, <= 1024)
__device__ __forceinline__ int block_scan_incl(int v) {
  int lane = threadIdx.x & 63;
  int wid = threadIdx.x >> 6;
  __shared__ int wsum[16];
  int incl = wave_scan_incl(v, lane);
  if (lane == 63) wsum[wid] = incl;
  __syncthreads();
  int nw = (int)(blockDim.x >> 6);
  if (wid == 0) {
    int s = (lane < nw) ? wsum[lane] : 0;
    s = wave_scan_incl(s, lane);
    if (lane < nw) wsum[lane] = s;
  }
  __syncthreads();
  if (wid > 0) incl += wsum[wid - 1];
  return incl;
}

__global__ void k_degree(const int* __restrict__ col, int* __restrict__ deg, int E) {
  int e = blockIdx.x * blockDim.x + threadIdx.x;
  if (e < E) atomicAdd(&deg[col[e]], 1);
}

__global__ void k_dis(const int* __restrict__ deg, float* __restrict__ dis, int n) {
  int i = blockIdx.x * blockDim.x + threadIdx.x;
  if (i < n) {
    int d = deg[i];
    dis[i] = (d > 0) ? rsqrtf((float)d) : 0.0f;
  }
}

__global__ void k_scan1(const int* __restrict__ deg, int* __restrict__ partial,
                        int* __restrict__ bsums, int n) {
  int i = blockIdx.x * SCAN_CHUNK + threadIdx.x;
  int v = (i < n) ? deg[i] : 0;
  int incl = block_scan_incl(v);
  if (i < n) partial[i] = incl - v;           // exclusive within chunk
  if (threadIdx.x == SCAN_CHUNK - 1) bsums[blockIdx.x] = incl;
}

__global__ void k_scan2(const int* __restrict__ bsums, int* __restrict__ boffs, int nb) {
  int i = threadIdx.x;
  int v = (i < nb) ? bsums[i] : 0;
  int incl = block_scan_incl(v);
  if (i < nb) boffs[i] = incl - v;            // exclusive block offsets
}

__global__ void k_scan3(const int* __restrict__ partial, const int* __restrict__ boffs,
                        int* __restrict__ offs, int* __restrict__ cursor, int n, int E) {
  int i = blockIdx.x * blockDim.x + threadIdx.x;
  if (i < n) {
    int o = partial[i] + boffs[i >> 10];      // >>10 == /SCAN_CHUNK
    offs[i] = o;
    cursor[i] = o;
  }
  if (i == n) offs[n] = E;                    // sum of degrees == E
}

__global__ void k_scatter(const int* __restrict__ row, const int* __restrict__ col,
                          const float* __restrict__ dis, int* __restrict__ cursor,
                          int* __restrict__ srcs, float* __restrict__ wn, int E) {
  int e = blockIdx.x * blockDim.x + threadIdx.x;
  if (e >= E) return;
  int r = row[e], c = col[e];
  int p = atomicAdd(&cursor[c], 1);
  srcs[p] = r;
  wn[p] = dis[r] * dis[c];
}

// one wave per node; lane = dim. acc += segment-sum; FINAL also applies /4.
template <bool FINAL>
__global__ void k_prop(const int* __restrict__ offs, const int* __restrict__ srcs,
                       const float* __restrict__ wn, const float* __restrict__ x,
                       float* __restrict__ xn, float* __restrict__ acc, int n) {
  int lane = threadIdx.x & 63;
  int node = blockIdx.x * (blockDim.x >> 6) + (threadIdx.x >> 6);
  if (node >= n) return;
  int beg = offs[node], end = offs[node + 1];
  float sum = 0.0f;
  for (int k = beg; k < end; ++k) {
    int j = srcs[k];
    float w = wn[k];
    sum = fmaf(w, x[((size_t)j << 6) + lane], sum);
  }
  size_t oi = ((size_t)node << 6) + lane;
  if (!FINAL) xn[oi] = sum;
  float a = acc[oi] + sum;
  acc[oi] = FINAL ? a * 0.25f : a;
}

extern "C" void kernel_launch(void* const* d_in, const int* in_sizes, int n_in,
                              void* d_out, int out_size, void* d_ws, size_t ws_size,
                              hipStream_t stream) {
  const int* edge = (const int*)d_in[0];
  const float* emb = (const float*)d_in[1];
  float* out = (float*)d_out;

  const int E = in_sizes[0] / 2;
  const int n = in_sizes[1] / 64;
  const int* row = edge;        // sources j
  const int* col = edge + E;    // targets i

  // ---- workspace carve-up (256B aligned) ----
  char* ws = (char*)d_ws;
  size_t off = 0;
  auto alloc = [&](size_t bytes) -> void* {
    void* p = ws + off;
    off += (bytes + 255) & ~(size_t)255;
    return p;
  };
  const int NB = (n + SCAN_CHUNK - 1) / SCAN_CHUNK;   // 98 for n=100000
  int*   deg     = (int*)  alloc((size_t)n * 4);
  float* dis     = (float*)alloc((size_t)n * 4);
  int*   partial = (int*)  alloc((size_t)n * 4);
  int*   offs    = (int*)  alloc((size_t)(n + 1) * 4);
  int*   cursor  = (int*)  alloc((size_t)n * 4);
  int*   bsums   = (int*)  alloc((size_t)NB * 4);
  int*   boffs   = (int*)  alloc((size_t)NB * 4);
  int*   srcs    = (int*)  alloc((size_t)E * 4);
  float* wn      = (float*)alloc((size_t)E * 4);
  float* bufA    = (float*)alloc((size_t)n * 64 * 4);
  float* bufB    = (float*)alloc((size_t)n * 64 * 4);
  (void)ws_size; (void)n_in; (void)out_size;

  // ---- build normalized CSR (by target node) ----
  hipMemsetAsync(deg, 0, (size_t)n * 4, stream);
  k_degree<<<(E + 255) / 256, 256, 0, stream>>>(col, deg, E);
  k_dis<<<(n + 255) / 256, 256, 0, stream>>>(deg, dis, n);
  k_scan1<<<NB, SCAN_CHUNK, 0, stream>>>(deg, partial, bsums, n);
  k_scan2<<<1, 128, 0, stream>>>(bsums, boffs, NB);   // NB <= 128
  k_scan3<<<(n + 256) / 256, 256, 0, stream>>>(partial, boffs, offs, cursor, n, E);
  k_scatter<<<(E + 255) / 256, 256, 0, stream>>>(row, col, dis, cursor, srcs, wn, E);

  // ---- acc = emb; then 3 propagation layers, last fuses /4 ----
  hipMemcpyAsync(out, emb, (size_t)n * 64 * 4, hipMemcpyDeviceToDevice, stream);
  const int pb = 256;                     // 4 waves/block
  const int pg = (n + 3) / 4;
  k_prop<false><<<pg, pb, 0, stream>>>(offs, srcs, wn, emb,  bufA, out, n);
  k_prop<false><<<pg, pb, 0, stream>>>(offs, srcs, wn, bufA, bufB, out, n);
  k_prop<true ><<<pg, pb, 0, stream>>>(offs, srcs, wn, bufB, bufA, out, n);
}

// Round 2
// 293.315 us; speedup vs baseline: 1.7724x; 1.7724x over previous
//
#include <hip/hip_runtime.h>

// LightGCN: deg -> norm -> CSR build -> 3x gather-scale-scatter -> mean of 4 layers.
// N=100000 nodes, E=1250000 edges, D=64.
// k_prop: one wave per node; 4 lane-groups of 16 process 4 edges concurrently,
// each lane holds float4 (4 dims); shfl_xor reduce at the end. Final layer fuses
// the 4-layer mean (groups 0/1/2 add emb/x1/x2 rows before the reduce).

#define SCAN_CHUNK 1024

__device__ __forceinline__ int wave_scan_incl(int v, int lane) {
#pragma unroll
  for (int off = 1; off < 64; off <<= 1) {
    int t = __shfl_up(v, off, 64);
    if (lane >= off) v += t;
  }
  return v;
}

__device__ __forceinline__ int block_scan_incl(int v) {
  int lane = threadIdx.x & 63;
  int wid = threadIdx.x >> 6;
  __shared__ int wsum[16];
  int incl = wave_scan_incl(v, lane);
  if (lane == 63) wsum[wid] = incl;
  __syncthreads();
  int nw = (int)(blockDim.x >> 6);
  if (wid == 0) {
    int s = (lane < nw) ? wsum[lane] : 0;
    s = wave_scan_incl(s, lane);
    if (lane < nw) wsum[lane] = s;
  }
  __syncthreads();
  if (wid > 0) incl += wsum[wid - 1];
  return incl;
}

__global__ void k_degree(const int* __restrict__ col, int* __restrict__ deg, int E) {
  int e = blockIdx.x * blockDim.x + threadIdx.x;
  if (e < E) atomicAdd(&deg[col[e]], 1);
}

// scan within chunk + fused deg_inv_sqrt
__global__ void k_scan1(const int* __restrict__ deg, int* __restrict__ partial,
                        int* __restrict__ bsums, float* __restrict__ dis, int n) {
  int i = blockIdx.x * SCAN_CHUNK + threadIdx.x;
  int v = (i < n) ? deg[i] : 0;
  int incl = block_scan_incl(v);
  if (i < n) {
    partial[i] = incl - v;                    // exclusive within chunk
    dis[i] = (v > 0) ? rsqrtf((float)v) : 0.0f;
  }
  if (threadIdx.x == SCAN_CHUNK - 1) bsums[blockIdx.x] = incl;
}

__global__ void k_scan2(const int* __restrict__ bsums, int* __restrict__ boffs, int nb) {
  int i = threadIdx.x;
  int v = (i < nb) ? bsums[i] : 0;
  int incl = block_scan_incl(v);
  if (i < nb) boffs[i] = incl - v;            // exclusive block offsets
}

__global__ void k_scan3(const int* __restrict__ partial, const int* __restrict__ boffs,
                        int* __restrict__ offs, int* __restrict__ cursor, int n, int E) {
  int i = blockIdx.x * blockDim.x + threadIdx.x;
  if (i < n) {
    int o = partial[i] + boffs[i >> 10];      // >>10 == /SCAN_CHUNK
    offs[i] = o;
    cursor[i] = o;
  }
  if (i == n) offs[n] = E;
}

__global__ void k_scatter(const int* __restrict__ row, const int* __restrict__ col,
                          const float* __restrict__ dis, int* __restrict__ cursor,
                          int2* __restrict__ edges, int E) {
  int e = blockIdx.x * blockDim.x + threadIdx.x;
  if (e >= E) return;
  int r = row[e], c = col[e];
  int p = atomicAdd(&cursor[c], 1);
  int2 rec;
  rec.x = r;
  rec.y = __float_as_int(dis[r] * dis[c]);
  edges[p] = rec;
}

// one wave per node. lane = 16*g + l: group g handles edges beg+g, +4, ...;
// lane covers dims 4l..4l+3 as float4. shfl_xor(16,32) reduces the 4 groups.
template <bool FINAL>
__global__ void k_prop(const int* __restrict__ offs, const int2* __restrict__ edges,
                       const float* __restrict__ x, float* __restrict__ xn,
                       const float* __restrict__ e0, const float* __restrict__ e1,
                       const float* __restrict__ e2, int n) {
  int lane = threadIdx.x & 63;
  int node = blockIdx.x * (blockDim.x >> 6) + (threadIdx.x >> 6);
  if (node >= n) return;
  int g = lane >> 4;
  int l = lane & 15;
  int beg = offs[node], end = offs[node + 1];
  size_t doff = (size_t)(l << 2);
  float4 s = make_float4(0.f, 0.f, 0.f, 0.f);
  for (int k = beg + g; k < end; k += 4) {
    int2 e = edges[k];
    float w = __int_as_float(e.y);
    float4 xr = *reinterpret_cast<const float4*>(x + (((size_t)e.x << 6) + doff));
    s.x = fmaf(w, xr.x, s.x);
    s.y = fmaf(w, xr.y, s.y);
    s.z = fmaf(w, xr.z, s.z);
    s.w = fmaf(w, xr.w, s.w);
  }
  if (FINAL) {
    // fold emb + x1 + x2 into the partials (one row per group), reduce sums all
    if (g < 3) {
      const float* ex = (g == 0) ? e0 : (g == 1) ? e1 : e2;
      float4 a = *reinterpret_cast<const float4*>(ex + (((size_t)node << 6) + doff));
      s.x += a.x; s.y += a.y; s.z += a.z; s.w += a.w;
    }
  }
#pragma unroll
  for (int off = 16; off < 64; off <<= 1) {
    s.x += __shfl_xor(s.x, off, 64);
    s.y += __shfl_xor(s.y, off, 64);
    s.z += __shfl_xor(s.z, off, 64);
    s.w += __shfl_xor(s.w, off, 64);
  }
  if (g == 0) {
    if (FINAL) { s.x *= 0.25f; s.y *= 0.25f; s.z *= 0.25f; s.w *= 0.25f; }
    *reinterpret_cast<float4*>(xn + (((size_t)node << 6) + doff)) = s;
  }
}

extern "C" void kernel_launch(void* const* d_in, const int* in_sizes, int n_in,
                              void* d_out, int out_size, void* d_ws, size_t ws_size,
                              hipStream_t stream) {
  const int* edge = (const int*)d_in[0];
  const float* emb = (const float*)d_in[1];
  float* out = (float*)d_out;

  const int E = in_sizes[0] / 2;
  const int n = in_sizes[1] / 64;
  const int* row = edge;        // sources j
  const int* col = edge + E;    // targets i

  char* ws = (char*)d_ws;
  size_t off = 0;
  auto alloc = [&](size_t bytes) -> void* {
    void* p = ws + off;
    off += (bytes + 255) & ~(size_t)255;
    return p;
  };
  const int NB = (n + SCAN_CHUNK - 1) / SCAN_CHUNK;
  int*   deg     = (int*)  alloc((size_t)n * 4);
  float* dis     = (float*)alloc((size_t)n * 4);
  int*   partial = (int*)  alloc((size_t)n * 4);
  int*   offs    = (int*)  alloc((size_t)(n + 1) * 4);
  int*   cursor  = (int*)  alloc((size_t)n * 4);
  int*   bsums   = (int*)  alloc((size_t)NB * 4);
  int*   boffs   = (int*)  alloc((size_t)NB * 4);
  int2*  edges   = (int2*) alloc((size_t)E * 8);
  float* bufA    = (float*)alloc((size_t)n * 64 * 4);
  float* bufB    = (float*)alloc((size_t)n * 64 * 4);
  (void)ws_size; (void)n_in; (void)out_size;

  // ---- build normalized CSR (by target node) ----
  hipMemsetAsync(deg, 0, (size_t)n * 4, stream);
  k_degree<<<(E + 255) / 256, 256, 0, stream>>>(col, deg, E);
  k_scan1<<<NB, SCAN_CHUNK, 0, stream>>>(deg, partial, bsums, dis, n);
  k_scan2<<<1, 128, 0, stream>>>(bsums, boffs, NB);
  k_scan3<<<(n + 256) / 256, 256, 0, stream>>>(partial, boffs, offs, cursor, n, E);
  k_scatter<<<(E + 255) / 256, 256, 0, stream>>>(row, col, dis, cursor, edges, E);

  // ---- 3 propagation layers; last fuses mean of {emb, x1, x2, x3} ----
  const int pb = 256;                 // 4 waves/block = 4 nodes/block
  const int pg = (n + 3) / 4;
  k_prop<false><<<pg, pb, 0, stream>>>(offs, edges, emb,  bufA, nullptr, nullptr, nullptr, n);
  k_prop<false><<<pg, pb, 0, stream>>>(offs, edges, bufA, bufB, nullptr, nullptr, nullptr, n);
  k_prop<true ><<<pg, pb, 0, stream>>>(offs, edges, bufB, out,  emb, bufA, bufB, n);
}